// Round 7
// baseline (408.933 us; speedup 1.0000x reference)
//
#include <hip/hip_runtime.h>
#include <hip/hip_bf16.h>
#include <cstdint>
#include <cstddef>

typedef unsigned short u16;
typedef __bf16 bf16x8 __attribute__((ext_vector_type(8)));
typedef u16 ushort8 __attribute__((ext_vector_type(8)));
typedef float f32x4 __attribute__((ext_vector_type(4)));

#define EMB_DIM 128
#define KDIM 256
#define HID 256
#define MTILE 64
#define NBLK 512   // 2 blocks/CU * 256 CU (LDS-limited)
#define NBUCK 1024 // >= ceil(100000/128)

// LDS layout (bytes)
#define XB       (2 * MTILE * 512)   // 65536: X double-buffer
#define PART_OFF XB                  // 2048: cross-wave logit partials
#define B1_OFF   (XB + 2048)         // 1024: b1 (f32[256])
#define AF2_OFF  (XB + 3072)         // 8192: W2 A-fragments
#define LDS_BYTES (XB + 2048 + 1024 + 8192)

static __device__ __forceinline__ u16 f2bf(float f) {
    uint32_t u = __builtin_bit_cast(uint32_t, f);
    u += 0x7fffu + ((u >> 16) & 1u);
    return (u16)(u >> 16);
}

// ---- prep kernels (validated R1-R6) ----
__global__ void prep_w1(const float* __restrict__ W1, u16* __restrict__ w1p) {
    int id = blockIdx.x * blockDim.x + threadIdx.x;   // 65536
    int j   = id & 7;
    int l   = (id >> 3) & 63;
    int kki = (id >> 9) & 7;
    int ntg = id >> 12;
    int k = kki * 32 + ((l >> 4) * 8) + j;
    int n = ntg * 16 + (l & 15);
    w1p[id] = f2bf(W1[k * HID + n]);
}

__global__ void prep_w2(const float* __restrict__ W2, u16* __restrict__ w2ap) {
    int id = blockIdx.x * blockDim.x + threadIdx.x;   // 4096
    if (id >= 4096) return;
    int j   = id & 7;
    int l   = (id >> 3) & 63;
    int kki = id >> 9;
    int m = l & 15;
    int g = (l >> 4) & 3;
    int k = kki * 32 + g * 4 + ((j >> 2) << 4) + (j & 3);
    w2ap[id] = (m < 2) ? f2bf(W2[k * 2 + m]) : (u16)0;
}

__global__ void prep_embs(const float* __restrict__ in, u16* __restrict__ out, int n) {
    int id = blockIdx.x * blockDim.x + threadIdx.x;
    size_t base = (size_t)id * 8;
    if (base + 8 <= (size_t)n) {
        float4 f0 = *reinterpret_cast<const float4*>(in + base);
        float4 f1 = *reinterpret_cast<const float4*>(in + base + 4);
        ushort8 h;
        h[0] = f2bf(f0.x); h[1] = f2bf(f0.y); h[2] = f2bf(f0.z); h[3] = f2bf(f0.w);
        h[4] = f2bf(f1.x); h[5] = f2bf(f1.y); h[6] = f2bf(f1.z); h[7] = f2bf(f1.w);
        *reinterpret_cast<ushort8*>(out + base) = h;
    }
}

// ---- n0-bucket counting sort (new R7) ----
__global__ void k_zero(int* __restrict__ histcur,           // hist+cursor (2*NBUCK)
                       int* __restrict__ spairs, int* __restrict__ seid,
                       int npairs, int ntiles) {
    int t = threadIdx.x;
    for (int i = t; i < 2 * NBUCK; i += 256) histcur[i] = 0;
    for (int i = npairs * 2 + t; i < ntiles * 128; i += 256) spairs[i] = 0;
    for (int i = npairs + t; i < ntiles * 64; i += 256) seid[i] = 0;
}

__global__ void k_hist(const int* __restrict__ nidx, int npairs, int* __restrict__ hist) {
    __shared__ int lh[NBUCK];
    int t = threadIdx.x;
    for (int i = t; i < NBUCK; i += 256) lh[i] = 0;
    __syncthreads();
    int stride = gridDim.x * blockDim.x;
    for (int e = blockIdx.x * blockDim.x + t; e < npairs; e += stride)
        atomicAdd(&lh[((const int2*)nidx)[e].x >> 7], 1);
    __syncthreads();
    for (int i = t; i < NBUCK; i += 256)
        if (lh[i]) atomicAdd(&hist[i], lh[i]);
}

__global__ void k_scan(const int* __restrict__ hist, int* __restrict__ cursor) {
    __shared__ int lsum[256];
    int t = threadIdx.x;
    int4 h = ((const int4*)hist)[t];             // bins 4t..4t+3
    int s3 = h.x + h.y + h.z + h.w;
    lsum[t] = s3;
    __syncthreads();
    for (int off = 1; off < 256; off <<= 1) {
        int v = (t >= off) ? lsum[t - off] : 0;
        __syncthreads();
        lsum[t] += v;
        __syncthreads();
    }
    int base = (t > 0) ? lsum[t - 1] : 0;
    ((int4*)cursor)[t] = make_int4(base, base + h.x, base + h.x + h.y,
                                   base + h.x + h.y + h.z);
}

__global__ void k_scatter(const int* __restrict__ nidx, int npairs,
                          int* __restrict__ cursor,
                          int2* __restrict__ spairs, int* __restrict__ seid) {
    int stride = gridDim.x * blockDim.x;
    for (int e = blockIdx.x * blockDim.x + threadIdx.x; e < npairs; e += stride) {
        int2 p = ((const int2*)nidx)[e];
        int pos = atomicAdd(&cursor[p.x >> 7], 1);
        spairs[pos] = p;
        seid[pos] = e;
    }
}

// ---- staging (validated R2-R6) ----
static __device__ __forceinline__ void gload_lds16(const void* g, void* s) {
    __builtin_amdgcn_global_load_lds(
        (const __attribute__((address_space(1))) unsigned int*)g,
        (__attribute__((address_space(3))) unsigned int*)s, 16, 0, 0);
}

static __device__ __forceinline__ void stage_tile(const u16* __restrict__ embT,
                                                  int vidx, unsigned char* xb,
                                                  int w, int l) {
    const int row_off = l >> 5;
    const int csel    = (l >> 4) & 1;
    const int c       = l & 31;
    #pragma unroll
    for (int i = 0; i < 8; ++i) {
        int n00 = __builtin_amdgcn_readlane(vidx, 4 * i + 0);
        int n01 = __builtin_amdgcn_readlane(vidx, 4 * i + 1);
        int n10 = __builtin_amdgcn_readlane(vidx, 4 * i + 2);
        int n11 = __builtin_amdgcn_readlane(vidx, 4 * i + 3);
        int na   = csel ? n01 : n00;
        int nb   = csel ? n11 : n10;
        int node = row_off ? nb : na;
        int r2   = 2 * i + row_off;
        int glow = (c ^ (r2 & 7)) & 15;
        const u16* src = embT + (size_t)node * 128 + glow * 8;
        gload_lds16(src, xb + (size_t)(w * 16 + 2 * i) * 512);
    }
}

// ---- main kernel: sorted contiguous chunks (R7) ----
__launch_bounds__(256, 2)
__global__ void edge_mlp_bf6(const u16* __restrict__ embT,
                             const int* __restrict__ spairs,
                             const int* __restrict__ seid,
                             const u16* __restrict__ w1p,
                             const u16* __restrict__ w2ap,
                             const float* __restrict__ b1,
                             const float* __restrict__ b2,
                             float* __restrict__ out,
                             int npairs, int ntiles, int q, int r) {
    __shared__ __align__(16) unsigned char lds[LDS_BYTES];
    const int t  = threadIdx.x;
    const int w  = t >> 6;
    const int l  = t & 63;
    const int lg = l >> 4;
    const int lc = l & 15;
    const int amax = ntiles * 128 - 1;
    const int smax = ntiles * 64 - 1;

    const int b = blockIdx.x;
    const int t0  = b * q + (b < r ? b : r);
    const int len = q + (b < r ? 1 : 0);
    if (len == 0) return;
    const int t1 = t0 + len;

    // ---- prologue: W1 -> registers, laundered (validated R6) ----
    bf16x8 wf1[4][8];
    #pragma unroll
    for (int ht = 0; ht < 4; ++ht)
        #pragma unroll
        for (int kki = 0; kki < 8; ++kki)
            wf1[ht][kki] = *reinterpret_cast<const bf16x8*>(
                w1p + (size_t)(((w * 4 + ht) * 8 + kki) * 64 + l) * 8);
    #pragma unroll
    for (int ht = 0; ht < 4; ++ht)
        #pragma unroll
        for (int kki = 0; kki < 8; ++kki)
            asm volatile("" : "+v"(wf1[ht][kki]));

    float b2c = b2[t & 1];
    asm volatile("" : "+v"(b2c));

    if (w == 0) {
        gload_lds16(b1 + l * 4, lds + B1_OFF);
    } else if (w == 1) {
        #pragma unroll
        for (int i = 0; i < 8; ++i)
            gload_lds16(w2ap + (size_t)i * 512 + l * 8, lds + AF2_OFF + i * 1024);
    }

    const int base0 = lc * 512 + ((lg ^ (lc & 3)) << 4) + (((lc >> 2) & 1) << 6);
    float2* part = reinterpret_cast<float2*>(lds + PART_OFF);

    // stage tile t0; prefetch indices + eid one iteration ahead
    {
        int gi = 2 * (t0 * 64 + w * 16) + l;
        int v0 = spairs[gi < amax ? gi : amax];
        stage_tile(embT, v0, lds, w, l);
    }
    int vnext, eidcur;
    {
        int gi = 2 * ((t0 + 1) * 64 + w * 16) + l;
        vnext = spairs[gi < amax ? gi : amax];
        int si = t0 * 64 + ((t & 127) >> 1);
        eidcur = seid[si < smax ? si : smax];
    }

    int buf = 0;
    for (int tile = t0; tile < t1; ++tile) {
        __syncthreads();   // sync1: stage(tile) complete (vmcnt0 drain)

        if (tile + 1 < t1)
            stage_tile(embT, vnext, lds + (buf ^ 1) * (MTILE * 512), w, l);
        int vfut, eidnext;
        {
            int gi = 2 * ((tile + 2) * 64 + w * 16) + l;
            vfut = spairs[gi < amax ? gi : amax];
            int si = (tile + 1) * 64 + ((t & 127) >> 1);
            eidnext = seid[si < smax ? si : smax];
        }

        // ---- GEMM1 (swapped): acc2[ht][et] = H^T[hidden][edge] ----
        const int vbuf = base0 + buf * (MTILE * 512);
        f32x4 acc2[4][4] = {};
        #pragma unroll
        for (int kki = 0; kki < 8; ++kki) {
            const int va = vbuf ^ (kki << 6);
            bf16x8 xf[4];
            #pragma unroll
            for (int et = 0; et < 4; ++et)
                xf[et] = *reinterpret_cast<const bf16x8*>(lds + va + et * 8192);
            #pragma unroll
            for (int ht = 0; ht < 4; ++ht)
                #pragma unroll
                for (int et = 0; et < 4; ++et)
                    acc2[ht][et] = __builtin_amdgcn_mfma_f32_16x16x32_bf16(
                        wf1[ht][kki], xf[et], acc2[ht][et], 0, 0, 0);
        }

        // ---- epilogue: relu(H+b1) then logits^T = W2^T @ . via MFMA ----
        float4 b1v[4];
        #pragma unroll
        for (int ht = 0; ht < 4; ++ht)
            b1v[ht] = *reinterpret_cast<const float4*>(
                lds + B1_OFF + (w * 64 + ht * 16 + lg * 4) * 4);
        bf16x8 af2[2];
        #pragma unroll
        for (int kk = 0; kk < 2; ++kk)
            af2[kk] = *reinterpret_cast<const bf16x8*>(
                lds + AF2_OFF + ((w * 2 + kk) * 64 + l) * 16);

        #pragma unroll
        for (int et = 0; et < 4; ++et) {
            uint32_t wd[4][2];
            #pragma unroll
            for (int ht = 0; ht < 4; ++ht) {
                float v0 = fmaxf(acc2[ht][et][0] + b1v[ht].x, 0.0f);
                float v1 = fmaxf(acc2[ht][et][1] + b1v[ht].y, 0.0f);
                float v2 = fmaxf(acc2[ht][et][2] + b1v[ht].z, 0.0f);
                float v3 = fmaxf(acc2[ht][et][3] + b1v[ht].w, 0.0f);
                asm("v_cvt_pk_bf16_f32 %0, %1, %2" : "=v"(wd[ht][0]) : "v"(v0), "v"(v1));
                asm("v_cvt_pk_bf16_f32 %0, %1, %2" : "=v"(wd[ht][1]) : "v"(v2), "v"(v3));
            }
            int4 lo4 = make_int4(wd[0][0], wd[0][1], wd[1][0], wd[1][1]);
            int4 hi4 = make_int4(wd[2][0], wd[2][1], wd[3][0], wd[3][1]);
            f32x4 a3 = {0.0f, 0.0f, 0.0f, 0.0f};
            a3 = __builtin_amdgcn_mfma_f32_16x16x32_bf16(
                af2[0], __builtin_bit_cast(bf16x8, lo4), a3, 0, 0, 0);
            a3 = __builtin_amdgcn_mfma_f32_16x16x32_bf16(
                af2[1], __builtin_bit_cast(bf16x8, hi4), a3, 0, 0, 0);
            if (l < 16)
                part[w * 64 + et * 16 + l] = make_float2(a3[0], a3[1]);
        }

        // sync2: LDS-only barrier — keep stage DMAs in flight
        asm volatile("s_waitcnt lgkmcnt(0)\n\ts_barrier" ::: "memory");

        if (t < 128 && tile * 64 + (t >> 1) < npairs) {
            const float* pf = reinterpret_cast<const float*>(part);
            float s = b2c + pf[t] + pf[128 + t] + pf[256 + t] + pf[384 + t];
            out[(size_t)eidcur * 2 + (t & 1)] = s;
        }

        vnext = vfut;
        eidcur = eidnext;
        buf ^= 1;
    }
}

// ---- fallback tier 2 (validated R6): unsorted persistent ----
__launch_bounds__(256, 2)
__global__ void edge_mlp_bf5(const u16* __restrict__ embT,
                             const int* __restrict__ nidx,
                             const u16* __restrict__ w1p,
                             const u16* __restrict__ w2ap,
                             const float* __restrict__ b1,
                             const float* __restrict__ b2,
                             float* __restrict__ out,
                             int npairs, int ntiles, int nb) {
    __shared__ __align__(16) unsigned char lds[LDS_BYTES];
    const int t  = threadIdx.x;
    const int w  = t >> 6;
    const int l  = t & 63;
    const int lg = l >> 4;
    const int lc = l & 15;
    const int gmax = 2 * npairs - 1;

    bf16x8 wf1[4][8];
    #pragma unroll
    for (int ht = 0; ht < 4; ++ht)
        #pragma unroll
        for (int kki = 0; kki < 8; ++kki)
            wf1[ht][kki] = *reinterpret_cast<const bf16x8*>(
                w1p + (size_t)(((w * 4 + ht) * 8 + kki) * 64 + l) * 8);
    #pragma unroll
    for (int ht = 0; ht < 4; ++ht)
        #pragma unroll
        for (int kki = 0; kki < 8; ++kki)
            asm volatile("" : "+v"(wf1[ht][kki]));

    float b2c = b2[t & 1];
    asm volatile("" : "+v"(b2c));

    if (w == 0) {
        gload_lds16(b1 + l * 4, lds + B1_OFF);
    } else if (w == 1) {
        #pragma unroll
        for (int i = 0; i < 8; ++i)
            gload_lds16(w2ap + (size_t)i * 512 + l * 8, lds + AF2_OFF + i * 1024);
    }

    const int base0 = lc * 512 + ((lg ^ (lc & 3)) << 4) + (((lc >> 2) & 1) << 6);
    float2* part = reinterpret_cast<float2*>(lds + PART_OFF);

    int tile = blockIdx.x;
    {
        int gi = 2 * (tile * 64 + w * 16) + l;
        int v0 = nidx[gi < gmax ? gi : gmax];
        stage_tile(embT, v0, lds, w, l);
    }
    int vnext;
    {
        int gi = 2 * ((tile + nb) * 64 + w * 16) + l;
        vnext = nidx[gi < gmax ? gi : gmax];
    }

    int buf = 0;
    for (; tile < ntiles; tile += nb) {
        __syncthreads();
        const int nxt = tile + nb;
        if (nxt < ntiles)
            stage_tile(embT, vnext, lds + (buf ^ 1) * (MTILE * 512), w, l);
        int vfut;
        {
            int gi = 2 * ((nxt + nb) * 64 + w * 16) + l;
            vfut = nidx[gi < gmax ? gi : gmax];
        }
        const int vbuf = base0 + buf * (MTILE * 512);
        f32x4 acc2[4][4] = {};
        #pragma unroll
        for (int kki = 0; kki < 8; ++kki) {
            const int va = vbuf ^ (kki << 6);
            bf16x8 xf[4];
            #pragma unroll
            for (int et = 0; et < 4; ++et)
                xf[et] = *reinterpret_cast<const bf16x8*>(lds + va + et * 8192);
            #pragma unroll
            for (int ht = 0; ht < 4; ++ht)
                #pragma unroll
                for (int et = 0; et < 4; ++et)
                    acc2[ht][et] = __builtin_amdgcn_mfma_f32_16x16x32_bf16(
                        wf1[ht][kki], xf[et], acc2[ht][et], 0, 0, 0);
        }
        float4 b1v[4];
        #pragma unroll
        for (int ht = 0; ht < 4; ++ht)
            b1v[ht] = *reinterpret_cast<const float4*>(
                lds + B1_OFF + (w * 64 + ht * 16 + lg * 4) * 4);
        bf16x8 af2[2];
        #pragma unroll
        for (int kk = 0; kk < 2; ++kk)
            af2[kk] = *reinterpret_cast<const bf16x8*>(
                lds + AF2_OFF + ((w * 2 + kk) * 64 + l) * 16);
        #pragma unroll
        for (int et = 0; et < 4; ++et) {
            uint32_t wd[4][2];
            #pragma unroll
            for (int ht = 0; ht < 4; ++ht) {
                float v0 = fmaxf(acc2[ht][et][0] + b1v[ht].x, 0.0f);
                float v1 = fmaxf(acc2[ht][et][1] + b1v[ht].y, 0.0f);
                float v2 = fmaxf(acc2[ht][et][2] + b1v[ht].z, 0.0f);
                float v3 = fmaxf(acc2[ht][et][3] + b1v[ht].w, 0.0f);
                asm("v_cvt_pk_bf16_f32 %0, %1, %2" : "=v"(wd[ht][0]) : "v"(v0), "v"(v1));
                asm("v_cvt_pk_bf16_f32 %0, %1, %2" : "=v"(wd[ht][1]) : "v"(v2), "v"(v3));
            }
            int4 lo4 = make_int4(wd[0][0], wd[0][1], wd[1][0], wd[1][1]);
            int4 hi4 = make_int4(wd[2][0], wd[2][1], wd[3][0], wd[3][1]);
            f32x4 a3 = {0.0f, 0.0f, 0.0f, 0.0f};
            a3 = __builtin_amdgcn_mfma_f32_16x16x32_bf16(
                af2[0], __builtin_bit_cast(bf16x8, lo4), a3, 0, 0, 0);
            a3 = __builtin_amdgcn_mfma_f32_16x16x32_bf16(
                af2[1], __builtin_bit_cast(bf16x8, hi4), a3, 0, 0, 0);
            if (l < 16)
                part[w * 64 + et * 16 + l] = make_float2(a3[0], a3[1]);
        }
        asm volatile("s_waitcnt lgkmcnt(0)\n\ts_barrier" ::: "memory");
        if (t < 128) {
            const float* pf = reinterpret_cast<const float*>(part);
            float s = b2c + pf[t] + pf[128 + t] + pf[256 + t] + pf[384 + t];
            int m = t >> 1;
            if (tile * 64 + m < npairs)
                out[(size_t)tile * 128 + t] = s;
        }
        vnext = vfut;
        buf ^= 1;
    }
}

// ---- fallback tier 3 (validated R1) ----
__launch_bounds__(256, 2)
__global__ void edge_mlp_f32g(const float* __restrict__ embs,
                              const int* __restrict__ nidx,
                              const u16* __restrict__ w1p,
                              const float* __restrict__ b1,
                              const float* __restrict__ W2,
                              const float* __restrict__ b2,
                              float* __restrict__ out,
                              int npairs) {
    __shared__ __align__(16) unsigned char lds[MTILE * 512 + 4 * MTILE * 2 * 4];
    const int t  = threadIdx.x;
    const int e0 = blockIdx.x * MTILE;
    {
        const int row = t >> 2;
        const int seg = t & 3;
        const int e = e0 + row;
        if (e < npairs) {
            const int i0 = nidx[2 * e];
            const int i1 = nidx[2 * e + 1];
            const float* src = (seg < 2) ? (embs + (size_t)i0 * EMB_DIM)
                                         : (embs + (size_t)i1 * EMB_DIM);
            const int cbase = (seg & 1) * 64;
            #pragma unroll
            for (int j = 0; j < 8; ++j) {
                const int c = cbase + j * 8;
                float4 f0 = *reinterpret_cast<const float4*>(src + c);
                float4 f1 = *reinterpret_cast<const float4*>(src + c + 4);
                ushort8 h;
                h[0] = f2bf(f0.x); h[1] = f2bf(f0.y);
                h[2] = f2bf(f0.z); h[3] = f2bf(f0.w);
                h[4] = f2bf(f1.x); h[5] = f2bf(f1.y);
                h[6] = f2bf(f1.z); h[7] = f2bf(f1.w);
                int off = row * 512 + (seg * 64 + j * 8) * 2;
                off ^= (row & 7) << 4;
                *reinterpret_cast<ushort8*>(lds + off) = h;
            }
        }
    }
    __syncthreads();
    const int w  = t >> 6;
    const int l  = t & 63;
    const int lg = l >> 4;
    const int lc = l & 15;
    f32x4 acc[4][4] = {};
    #pragma unroll
    for (int kki = 0; kki < 8; ++kki) {
        const int krow = kki * 32 + lg * 8;
        bf16x8 a[4], bb[4];
        #pragma unroll
        for (int mt = 0; mt < 4; ++mt) {
            const int row = mt * 16 + lc;
            int off = row * 512 + krow * 2;
            off ^= (row & 7) << 4;
            a[mt] = *reinterpret_cast<const bf16x8*>(lds + off);
        }
        #pragma unroll
        for (int nt = 0; nt < 4; ++nt)
            bb[nt] = *reinterpret_cast<const bf16x8*>(
                w1p + (size_t)(((w * 4 + nt) * 8 + kki) * 64 + l) * 8);
        #pragma unroll
        for (int mt = 0; mt < 4; ++mt)
            #pragma unroll
            for (int nt = 0; nt < 4; ++nt)
                acc[mt][nt] = __builtin_amdgcn_mfma_f32_16x16x32_bf16(
                    a[mt], bb[nt], acc[mt][nt], 0, 0, 0);
    }
    float p0[4][4] = {}, p1[4][4] = {};
    #pragma unroll
    for (int nt = 0; nt < 4; ++nt) {
        const int n = w * 64 + nt * 16 + lc;
        const float bnv = b1[n];
        const float w20 = W2[2 * n];
        const float w21 = W2[2 * n + 1];
        #pragma unroll
        for (int mt = 0; mt < 4; ++mt)
            #pragma unroll
            for (int rr = 0; rr < 4; ++rr) {
                float v = fmaxf(acc[mt][nt][rr] + bnv, 0.0f);
                p0[mt][rr] = fmaf(v, w20, p0[mt][rr]);
                p1[mt][rr] = fmaf(v, w21, p1[mt][rr]);
            }
    }
    #pragma unroll
    for (int mt = 0; mt < 4; ++mt)
        #pragma unroll
        for (int rr = 0; rr < 4; ++rr) {
            float a0 = p0[mt][rr], a1 = p1[mt][rr];
            #pragma unroll
            for (int mask = 1; mask < 16; mask <<= 1) {
                a0 += __shfl_xor(a0, mask);
                a1 += __shfl_xor(a1, mask);
            }
            p0[mt][rr] = a0; p1[mt][rr] = a1;
        }
    float* part = reinterpret_cast<float*>(lds + MTILE * 512);
    if (lc == 0) {
        #pragma unroll
        for (int mt = 0; mt < 4; ++mt)
            #pragma unroll
            for (int rr = 0; rr < 4; ++rr) {
                const int m = mt * 16 + lg * 4 + rr;
                part[(w * MTILE + m) * 2 + 0] = p0[mt][rr];
                part[(w * MTILE + m) * 2 + 1] = p1[mt][rr];
            }
    }
    __syncthreads();
    if (t < 2 * MTILE) {
        const int m = t >> 1, c = t & 1;
        if (e0 + m < npairs) {
            float s = b2[c];
            #pragma unroll
            for (int ww = 0; ww < 4; ++ww)
                s += part[(ww * MTILE + m) * 2 + c];
            out[(size_t)(e0 + m) * 2 + c] = s;
        }
    }
}

extern "C" void kernel_launch(void* const* d_in, const int* in_sizes, int n_in,
                              void* d_out, int out_size, void* d_ws, size_t ws_size,
                              hipStream_t stream) {
    const float* embs = (const float*)d_in[0];
    const int*   nidx = (const int*)d_in[1];
    const float* W1   = (const float*)d_in[2];
    const float* b1   = (const float*)d_in[3];
    const float* W2   = (const float*)d_in[4];
    const float* b2   = (const float*)d_in[5];
    float* out = (float*)d_out;

    const int nemb   = in_sizes[0];
    const int npairs = in_sizes[1] / 2;
    const int ntiles = (npairs + MTILE - 1) / MTILE;

    u16* w1p = (u16*)d_ws;                                   // 128 KiB @0
    prep_w1<<<(KDIM * HID) / 256, 256, 0, stream>>>(W1, w1p);

    const size_t w2_off   = 131072;
    const size_t hist_off = w2_off + 8192;                   // NBUCK ints
    const size_t cur_off  = hist_off + NBUCK * 4;
    const size_t embT_off = cur_off + NBUCK * 4;
    const size_t embT_end = embT_off + (size_t)nemb * 2;
    const size_t sp_off   = (embT_end + 255) & ~(size_t)255;
    const size_t se_off   = sp_off + (size_t)ntiles * 128 * 4;
    const size_t need_sort = se_off + (size_t)ntiles * 64 * 4;
    const size_t need_bf   = embT_end;

    if (ws_size >= need_bf) {
        u16* w2ap = (u16*)((char*)d_ws + w2_off);
        u16* embT = (u16*)((char*)d_ws + embT_off);
        prep_w2<<<16, 256, 0, stream>>>(W2, w2ap);
        prep_embs<<<(nemb + 2047) / 2048, 256, 0, stream>>>(embs, embT, nemb);

        if (ws_size >= need_sort) {
            int* hist    = (int*)((char*)d_ws + hist_off);
            int* cursor  = (int*)((char*)d_ws + cur_off);
            int* spairs  = (int*)((char*)d_ws + sp_off);
            int* seid    = (int*)((char*)d_ws + se_off);
            k_zero<<<1, 256, 0, stream>>>(hist, spairs, seid, npairs, ntiles);
            k_hist<<<256, 256, 0, stream>>>(nidx, npairs, hist);
            k_scan<<<1, 256, 0, stream>>>(hist, cursor);
            k_scatter<<<256, 256, 0, stream>>>(nidx, npairs, cursor,
                                               (int2*)spairs, seid);
            const int nb = NBLK < ntiles ? NBLK : ntiles;
            const int q = ntiles / nb, rr = ntiles % nb;
            edge_mlp_bf6<<<nb, 256, 0, stream>>>(embT, spairs, seid, w1p, w2ap,
                                                 b1, b2, out, npairs, ntiles, q, rr);
        } else {
            const int nb = NBLK < ntiles ? NBLK : ntiles;
            edge_mlp_bf5<<<nb, 256, 0, stream>>>(embT, nidx, w1p, w2ap, b1, b2,
                                                 out, npairs, ntiles, nb);
        }
    } else {
        edge_mlp_f32g<<<ntiles, 256, 0, stream>>>(embs, nidx, w1p, b1, W2, b2,
                                                  out, npairs);
    }
}

// Round 8
// 202.335 us; speedup vs baseline: 2.0211x; 2.0211x over previous
//
#include <hip/hip_runtime.h>
#include <hip/hip_bf16.h>
#include <cstdint>
#include <cstddef>

typedef unsigned short u16;
typedef __bf16 bf16x8 __attribute__((ext_vector_type(8)));
typedef u16 ushort8 __attribute__((ext_vector_type(8)));
typedef float f32x4 __attribute__((ext_vector_type(4)));

#define EMB_DIM 128
#define KDIM 256
#define HID 256
#define MTILE 64
#define NBLK 512   // 2 blocks/CU * 256 CU (LDS-limited)
#define NBUCK 1024 // >= ceil(100000/128)

// LDS layout (bytes)
#define XB       (2 * MTILE * 512)   // 65536: X double-buffer
#define PART_OFF XB                  // 2048: cross-wave logit partials
#define B1_OFF   (XB + 2048)         // 1024: b1 (f32[256])
#define AF2_OFF  (XB + 3072)         // 8192: W2 A-fragments
#define LDS_BYTES (XB + 2048 + 1024 + 8192)

static __device__ __forceinline__ u16 f2bf(float f) {
    uint32_t u = __builtin_bit_cast(uint32_t, f);
    u += 0x7fffu + ((u >> 16) & 1u);
    return (u16)(u >> 16);
}

// ---- prep kernels (validated R1-R7) ----
__global__ void prep_w1(const float* __restrict__ W1, u16* __restrict__ w1p) {
    int id = blockIdx.x * blockDim.x + threadIdx.x;   // 65536
    int j   = id & 7;
    int l   = (id >> 3) & 63;
    int kki = (id >> 9) & 7;
    int ntg = id >> 12;
    int k = kki * 32 + ((l >> 4) * 8) + j;
    int n = ntg * 16 + (l & 15);
    w1p[id] = f2bf(W1[k * HID + n]);
}

__global__ void prep_w2(const float* __restrict__ W2, u16* __restrict__ w2ap) {
    int id = blockIdx.x * blockDim.x + threadIdx.x;   // 4096
    if (id >= 4096) return;
    int j   = id & 7;
    int l   = (id >> 3) & 63;
    int kki = id >> 9;
    int m = l & 15;
    int g = (l >> 4) & 3;
    int k = kki * 32 + g * 4 + ((j >> 2) << 4) + (j & 3);
    w2ap[id] = (m < 2) ? f2bf(W2[k * 2 + m]) : (u16)0;
}

__global__ void prep_embs(const float* __restrict__ in, u16* __restrict__ out, int n) {
    int id = blockIdx.x * blockDim.x + threadIdx.x;
    size_t base = (size_t)id * 8;
    if (base + 8 <= (size_t)n) {
        float4 f0 = *reinterpret_cast<const float4*>(in + base);
        float4 f1 = *reinterpret_cast<const float4*>(in + base + 4);
        ushort8 h;
        h[0] = f2bf(f0.x); h[1] = f2bf(f0.y); h[2] = f2bf(f0.z); h[3] = f2bf(f0.w);
        h[4] = f2bf(f1.x); h[5] = f2bf(f1.y); h[6] = f2bf(f1.z); h[7] = f2bf(f1.w);
        *reinterpret_cast<ushort8*>(out + base) = h;
    }
}

// ---- n0-bucket counting sort ----
__global__ void k_zero(int* __restrict__ histcur,           // hist+cursor (2*NBUCK)
                       int* __restrict__ spairs, int* __restrict__ seid,
                       int npairs, int ntiles) {
    int t = threadIdx.x;
    for (int i = t; i < 2 * NBUCK; i += 256) histcur[i] = 0;
    for (int i = npairs * 2 + t; i < ntiles * 128; i += 256) spairs[i] = 0;
    for (int i = npairs + t; i < ntiles * 64; i += 256) seid[i] = 0;
}

__global__ void k_hist(const int* __restrict__ nidx, int npairs, int* __restrict__ hist) {
    __shared__ int lh[NBUCK];
    int t = threadIdx.x;
    for (int i = t; i < NBUCK; i += 256) lh[i] = 0;
    __syncthreads();
    int stride = gridDim.x * blockDim.x;
    for (int e = blockIdx.x * blockDim.x + t; e < npairs; e += stride)
        atomicAdd(&lh[((const int2*)nidx)[e].x >> 7], 1);
    __syncthreads();
    for (int i = t; i < NBUCK; i += 256)
        if (lh[i]) atomicAdd(&hist[i], lh[i]);
}

__global__ void k_scan(const int* __restrict__ hist, int* __restrict__ cursor) {
    __shared__ int lsum[256];
    int t = threadIdx.x;
    int4 h = ((const int4*)hist)[t];             // bins 4t..4t+3
    int s3 = h.x + h.y + h.z + h.w;
    lsum[t] = s3;
    __syncthreads();
    for (int off = 1; off < 256; off <<= 1) {
        int v = (t >= off) ? lsum[t - off] : 0;
        __syncthreads();
        lsum[t] += v;
        __syncthreads();
    }
    int base = (t > 0) ? lsum[t - 1] : 0;
    ((int4*)cursor)[t] = make_int4(base, base + h.x, base + h.x + h.y,
                                   base + h.x + h.y + h.z);
}

// Block-aggregated scatter (R8): ONE global atomic per (block,bucket), LDS
// ranks within the block. 200K spread atomics instead of 1M over 782 addrs.
__global__ void k_scatter2(const int* __restrict__ nidx, int npairs,
                           int* __restrict__ cursor,
                           int2* __restrict__ spairs, int* __restrict__ seid) {
    __shared__ int lbase[NBUCK];
    __shared__ int lcur[NBUCK];
    const int t = threadIdx.x;
    const int chunk = (npairs + gridDim.x - 1) / gridDim.x;
    const int e0 = blockIdx.x * chunk;
    const int e1 = (e0 + chunk < npairs) ? e0 + chunk : npairs;
    for (int i = t; i < NBUCK; i += 256) { lbase[i] = 0; lcur[i] = 0; }
    __syncthreads();
    for (int e = e0 + t; e < e1; e += 256)
        atomicAdd(&lbase[((const int2*)nidx)[e].x >> 7], 1);
    __syncthreads();
    for (int i = t; i < NBUCK; i += 256) {
        int c = lbase[i];
        lbase[i] = c ? atomicAdd(&cursor[i], c) : 0;
    }
    __syncthreads();
    for (int e = e0 + t; e < e1; e += 256) {
        int2 p = ((const int2*)nidx)[e];
        int b = p.x >> 7;
        int r = atomicAdd(&lcur[b], 1);
        int pos = lbase[b] + r;
        spairs[pos] = p;
        seid[pos] = e;
    }
}

// ---- staging (validated R2-R7) ----
static __device__ __forceinline__ void gload_lds16(const void* g, void* s) {
    __builtin_amdgcn_global_load_lds(
        (const __attribute__((address_space(1))) unsigned int*)g,
        (__attribute__((address_space(3))) unsigned int*)s, 16, 0, 0);
}

static __device__ __forceinline__ void stage_tile(const u16* __restrict__ embT,
                                                  int vidx, unsigned char* xb,
                                                  int w, int l) {
    const int row_off = l >> 5;
    const int csel    = (l >> 4) & 1;
    const int c       = l & 31;
    #pragma unroll
    for (int i = 0; i < 8; ++i) {
        int n00 = __builtin_amdgcn_readlane(vidx, 4 * i + 0);
        int n01 = __builtin_amdgcn_readlane(vidx, 4 * i + 1);
        int n10 = __builtin_amdgcn_readlane(vidx, 4 * i + 2);
        int n11 = __builtin_amdgcn_readlane(vidx, 4 * i + 3);
        int na   = csel ? n01 : n00;
        int nb   = csel ? n11 : n10;
        int node = row_off ? nb : na;
        int r2   = 2 * i + row_off;
        int glow = (c ^ (r2 & 7)) & 15;
        const u16* src = embT + (size_t)node * 128 + glow * 8;
        gload_lds16(src, xb + (size_t)(w * 16 + 2 * i) * 512);
    }
}

// ---- main kernel: sorted contiguous chunks (validated R7) ----
__launch_bounds__(256, 2)
__global__ void edge_mlp_bf6(const u16* __restrict__ embT,
                             const int* __restrict__ spairs,
                             const int* __restrict__ seid,
                             const u16* __restrict__ w1p,
                             const u16* __restrict__ w2ap,
                             const float* __restrict__ b1,
                             const float* __restrict__ b2,
                             float* __restrict__ out,
                             int npairs, int ntiles, int q, int r) {
    __shared__ __align__(16) unsigned char lds[LDS_BYTES];
    const int t  = threadIdx.x;
    const int w  = t >> 6;
    const int l  = t & 63;
    const int lg = l >> 4;
    const int lc = l & 15;
    const int amax = ntiles * 128 - 1;
    const int smax = ntiles * 64 - 1;

    const int b = blockIdx.x;
    const int t0  = b * q + (b < r ? b : r);
    const int len = q + (b < r ? 1 : 0);
    if (len == 0) return;
    const int t1 = t0 + len;

    bf16x8 wf1[4][8];
    #pragma unroll
    for (int ht = 0; ht < 4; ++ht)
        #pragma unroll
        for (int kki = 0; kki < 8; ++kki)
            wf1[ht][kki] = *reinterpret_cast<const bf16x8*>(
                w1p + (size_t)(((w * 4 + ht) * 8 + kki) * 64 + l) * 8);
    #pragma unroll
    for (int ht = 0; ht < 4; ++ht)
        #pragma unroll
        for (int kki = 0; kki < 8; ++kki)
            asm volatile("" : "+v"(wf1[ht][kki]));

    float b2c = b2[t & 1];
    asm volatile("" : "+v"(b2c));

    if (w == 0) {
        gload_lds16(b1 + l * 4, lds + B1_OFF);
    } else if (w == 1) {
        #pragma unroll
        for (int i = 0; i < 8; ++i)
            gload_lds16(w2ap + (size_t)i * 512 + l * 8, lds + AF2_OFF + i * 1024);
    }

    const int base0 = lc * 512 + ((lg ^ (lc & 3)) << 4) + (((lc >> 2) & 1) << 6);
    float2* part = reinterpret_cast<float2*>(lds + PART_OFF);

    {
        int gi = 2 * (t0 * 64 + w * 16) + l;
        int v0 = spairs[gi < amax ? gi : amax];
        stage_tile(embT, v0, lds, w, l);
    }
    int vnext, eidcur;
    {
        int gi = 2 * ((t0 + 1) * 64 + w * 16) + l;
        vnext = spairs[gi < amax ? gi : amax];
        int si = t0 * 64 + ((t & 127) >> 1);
        eidcur = seid[si < smax ? si : smax];
    }

    int buf = 0;
    for (int tile = t0; tile < t1; ++tile) {
        __syncthreads();   // sync1: stage(tile) complete (vmcnt0 drain)

        if (tile + 1 < t1)
            stage_tile(embT, vnext, lds + (buf ^ 1) * (MTILE * 512), w, l);
        int vfut, eidnext;
        {
            int gi = 2 * ((tile + 2) * 64 + w * 16) + l;
            vfut = spairs[gi < amax ? gi : amax];
            int si = (tile + 1) * 64 + ((t & 127) >> 1);
            eidnext = seid[si < smax ? si : smax];
        }

        const int vbuf = base0 + buf * (MTILE * 512);
        f32x4 acc2[4][4] = {};
        #pragma unroll
        for (int kki = 0; kki < 8; ++kki) {
            const int va = vbuf ^ (kki << 6);
            bf16x8 xf[4];
            #pragma unroll
            for (int et = 0; et < 4; ++et)
                xf[et] = *reinterpret_cast<const bf16x8*>(lds + va + et * 8192);
            #pragma unroll
            for (int ht = 0; ht < 4; ++ht)
                #pragma unroll
                for (int et = 0; et < 4; ++et)
                    acc2[ht][et] = __builtin_amdgcn_mfma_f32_16x16x32_bf16(
                        wf1[ht][kki], xf[et], acc2[ht][et], 0, 0, 0);
        }

        float4 b1v[4];
        #pragma unroll
        for (int ht = 0; ht < 4; ++ht)
            b1v[ht] = *reinterpret_cast<const float4*>(
                lds + B1_OFF + (w * 64 + ht * 16 + lg * 4) * 4);
        bf16x8 af2[2];
        #pragma unroll
        for (int kk = 0; kk < 2; ++kk)
            af2[kk] = *reinterpret_cast<const bf16x8*>(
                lds + AF2_OFF + ((w * 2 + kk) * 64 + l) * 16);

        #pragma unroll
        for (int et = 0; et < 4; ++et) {
            uint32_t wd[4][2];
            #pragma unroll
            for (int ht = 0; ht < 4; ++ht) {
                float v0 = fmaxf(acc2[ht][et][0] + b1v[ht].x, 0.0f);
                float v1 = fmaxf(acc2[ht][et][1] + b1v[ht].y, 0.0f);
                float v2 = fmaxf(acc2[ht][et][2] + b1v[ht].z, 0.0f);
                float v3 = fmaxf(acc2[ht][et][3] + b1v[ht].w, 0.0f);
                asm("v_cvt_pk_bf16_f32 %0, %1, %2" : "=v"(wd[ht][0]) : "v"(v0), "v"(v1));
                asm("v_cvt_pk_bf16_f32 %0, %1, %2" : "=v"(wd[ht][1]) : "v"(v2), "v"(v3));
            }
            int4 lo4 = make_int4(wd[0][0], wd[0][1], wd[1][0], wd[1][1]);
            int4 hi4 = make_int4(wd[2][0], wd[2][1], wd[3][0], wd[3][1]);
            f32x4 a3 = {0.0f, 0.0f, 0.0f, 0.0f};
            a3 = __builtin_amdgcn_mfma_f32_16x16x32_bf16(
                af2[0], __builtin_bit_cast(bf16x8, lo4), a3, 0, 0, 0);
            a3 = __builtin_amdgcn_mfma_f32_16x16x32_bf16(
                af2[1], __builtin_bit_cast(bf16x8, hi4), a3, 0, 0, 0);
            if (l < 16)
                part[w * 64 + et * 16 + l] = make_float2(a3[0], a3[1]);
        }

        asm volatile("s_waitcnt lgkmcnt(0)\n\ts_barrier" ::: "memory");

        if (t < 128 && tile * 64 + (t >> 1) < npairs) {
            const float* pf = reinterpret_cast<const float*>(part);
            float s = b2c + pf[t] + pf[128 + t] + pf[256 + t] + pf[384 + t];
            out[(size_t)eidcur * 2 + (t & 1)] = s;
        }

        vnext = vfut;
        eidcur = eidnext;
        buf ^= 1;
    }
}

// ---- fallback tier 2 (validated R6): unsorted persistent ----
__launch_bounds__(256, 2)
__global__ void edge_mlp_bf5(const u16* __restrict__ embT,
                             const int* __restrict__ nidx,
                             const u16* __restrict__ w1p,
                             const u16* __restrict__ w2ap,
                             const float* __restrict__ b1,
                             const float* __restrict__ b2,
                             float* __restrict__ out,
                             int npairs, int ntiles, int nb) {
    __shared__ __align__(16) unsigned char lds[LDS_BYTES];
    const int t  = threadIdx.x;
    const int w  = t >> 6;
    const int l  = t & 63;
    const int lg = l >> 4;
    const int lc = l & 15;
    const int gmax = 2 * npairs - 1;

    bf16x8 wf1[4][8];
    #pragma unroll
    for (int ht = 0; ht < 4; ++ht)
        #pragma unroll
        for (int kki = 0; kki < 8; ++kki)
            wf1[ht][kki] = *reinterpret_cast<const bf16x8*>(
                w1p + (size_t)(((w * 4 + ht) * 8 + kki) * 64 + l) * 8);
    #pragma unroll
    for (int ht = 0; ht < 4; ++ht)
        #pragma unroll
        for (int kki = 0; kki < 8; ++kki)
            asm volatile("" : "+v"(wf1[ht][kki]));

    float b2c = b2[t & 1];
    asm volatile("" : "+v"(b2c));

    if (w == 0) {
        gload_lds16(b1 + l * 4, lds + B1_OFF);
    } else if (w == 1) {
        #pragma unroll
        for (int i = 0; i < 8; ++i)
            gload_lds16(w2ap + (size_t)i * 512 + l * 8, lds + AF2_OFF + i * 1024);
    }

    const int base0 = lc * 512 + ((lg ^ (lc & 3)) << 4) + (((lc >> 2) & 1) << 6);
    float2* part = reinterpret_cast<float2*>(lds + PART_OFF);

    int tile = blockIdx.x;
    {
        int gi = 2 * (tile * 64 + w * 16) + l;
        int v0 = nidx[gi < gmax ? gi : gmax];
        stage_tile(embT, v0, lds, w, l);
    }
    int vnext;
    {
        int gi = 2 * ((tile + nb) * 64 + w * 16) + l;
        vnext = nidx[gi < gmax ? gi : gmax];
    }

    int buf = 0;
    for (; tile < ntiles; tile += nb) {
        __syncthreads();
        const int nxt = tile + nb;
        if (nxt < ntiles)
            stage_tile(embT, vnext, lds + (buf ^ 1) * (MTILE * 512), w, l);
        int vfut;
        {
            int gi = 2 * ((nxt + nb) * 64 + w * 16) + l;
            vfut = nidx[gi < gmax ? gi : gmax];
        }
        const int vbuf = base0 + buf * (MTILE * 512);
        f32x4 acc2[4][4] = {};
        #pragma unroll
        for (int kki = 0; kki < 8; ++kki) {
            const int va = vbuf ^ (kki << 6);
            bf16x8 xf[4];
            #pragma unroll
            for (int et = 0; et < 4; ++et)
                xf[et] = *reinterpret_cast<const bf16x8*>(lds + va + et * 8192);
            #pragma unroll
            for (int ht = 0; ht < 4; ++ht)
                #pragma unroll
                for (int et = 0; et < 4; ++et)
                    acc2[ht][et] = __builtin_amdgcn_mfma_f32_16x16x32_bf16(
                        wf1[ht][kki], xf[et], acc2[ht][et], 0, 0, 0);
        }
        float4 b1v[4];
        #pragma unroll
        for (int ht = 0; ht < 4; ++ht)
            b1v[ht] = *reinterpret_cast<const float4*>(
                lds + B1_OFF + (w * 64 + ht * 16 + lg * 4) * 4);
        bf16x8 af2[2];
        #pragma unroll
        for (int kk = 0; kk < 2; ++kk)
            af2[kk] = *reinterpret_cast<const bf16x8*>(
                lds + AF2_OFF + ((w * 2 + kk) * 64 + l) * 16);
        #pragma unroll
        for (int et = 0; et < 4; ++et) {
            uint32_t wd[4][2];
            #pragma unroll
            for (int ht = 0; ht < 4; ++ht) {
                float v0 = fmaxf(acc2[ht][et][0] + b1v[ht].x, 0.0f);
                float v1 = fmaxf(acc2[ht][et][1] + b1v[ht].y, 0.0f);
                float v2 = fmaxf(acc2[ht][et][2] + b1v[ht].z, 0.0f);
                float v3 = fmaxf(acc2[ht][et][3] + b1v[ht].w, 0.0f);
                asm("v_cvt_pk_bf16_f32 %0, %1, %2" : "=v"(wd[ht][0]) : "v"(v0), "v"(v1));
                asm("v_cvt_pk_bf16_f32 %0, %1, %2" : "=v"(wd[ht][1]) : "v"(v2), "v"(v3));
            }
            int4 lo4 = make_int4(wd[0][0], wd[0][1], wd[1][0], wd[1][1]);
            int4 hi4 = make_int4(wd[2][0], wd[2][1], wd[3][0], wd[3][1]);
            f32x4 a3 = {0.0f, 0.0f, 0.0f, 0.0f};
            a3 = __builtin_amdgcn_mfma_f32_16x16x32_bf16(
                af2[0], __builtin_bit_cast(bf16x8, lo4), a3, 0, 0, 0);
            a3 = __builtin_amdgcn_mfma_f32_16x16x32_bf16(
                af2[1], __builtin_bit_cast(bf16x8, hi4), a3, 0, 0, 0);
            if (l < 16)
                part[w * 64 + et * 16 + l] = make_float2(a3[0], a3[1]);
        }
        asm volatile("s_waitcnt lgkmcnt(0)\n\ts_barrier" ::: "memory");
        if (t < 128) {
            const float* pf = reinterpret_cast<const float*>(part);
            float s = b2c + pf[t] + pf[128 + t] + pf[256 + t] + pf[384 + t];
            int m = t >> 1;
            if (tile * 64 + m < npairs)
                out[(size_t)tile * 128 + t] = s;
        }
        vnext = vfut;
        buf ^= 1;
    }
}

// ---- fallback tier 3 (validated R1) ----
__launch_bounds__(256, 2)
__global__ void edge_mlp_f32g(const float* __restrict__ embs,
                              const int* __restrict__ nidx,
                              const u16* __restrict__ w1p,
                              const float* __restrict__ b1,
                              const float* __restrict__ W2,
                              const float* __restrict__ b2,
                              float* __restrict__ out,
                              int npairs) {
    __shared__ __align__(16) unsigned char lds[MTILE * 512 + 4 * MTILE * 2 * 4];
    const int t  = threadIdx.x;
    const int e0 = blockIdx.x * MTILE;
    {
        const int row = t >> 2;
        const int seg = t & 3;
        const int e = e0 + row;
        if (e < npairs) {
            const int i0 = nidx[2 * e];
            const int i1 = nidx[2 * e + 1];
            const float* src = (seg < 2) ? (embs + (size_t)i0 * EMB_DIM)
                                         : (embs + (size_t)i1 * EMB_DIM);
            const int cbase = (seg & 1) * 64;
            #pragma unroll
            for (int j = 0; j < 8; ++j) {
                const int c = cbase + j * 8;
                float4 f0 = *reinterpret_cast<const float4*>(src + c);
                float4 f1 = *reinterpret_cast<const float4*>(src + c + 4);
                ushort8 h;
                h[0] = f2bf(f0.x); h[1] = f2bf(f0.y);
                h[2] = f2bf(f0.z); h[3] = f2bf(f0.w);
                h[4] = f2bf(f1.x); h[5] = f2bf(f1.y);
                h[6] = f2bf(f1.z); h[7] = f2bf(f1.w);
                int off = row * 512 + (seg * 64 + j * 8) * 2;
                off ^= (row & 7) << 4;
                *reinterpret_cast<ushort8*>(lds + off) = h;
            }
        }
    }
    __syncthreads();
    const int w  = t >> 6;
    const int l  = t & 63;
    const int lg = l >> 4;
    const int lc = l & 15;
    f32x4 acc[4][4] = {};
    #pragma unroll
    for (int kki = 0; kki < 8; ++kki) {
        const int krow = kki * 32 + lg * 8;
        bf16x8 a[4], bb[4];
        #pragma unroll
        for (int mt = 0; mt < 4; ++mt) {
            const int row = mt * 16 + lc;
            int off = row * 512 + krow * 2;
            off ^= (row & 7) << 4;
            a[mt] = *reinterpret_cast<const bf16x8*>(lds + off);
        }
        #pragma unroll
        for (int nt = 0; nt < 4; ++nt)
            bb[nt] = *reinterpret_cast<const bf16x8*>(
                w1p + (size_t)(((w * 4 + nt) * 8 + kki) * 64 + l) * 8);
        #pragma unroll
        for (int mt = 0; mt < 4; ++mt)
            #pragma unroll
            for (int nt = 0; nt < 4; ++nt)
                acc[mt][nt] = __builtin_amdgcn_mfma_f32_16x16x32_bf16(
                    a[mt], bb[nt], acc[mt][nt], 0, 0, 0);
    }
    float p0[4][4] = {}, p1[4][4] = {};
    #pragma unroll
    for (int nt = 0; nt < 4; ++nt) {
        const int n = w * 64 + nt * 16 + lc;
        const float bnv = b1[n];
        const float w20 = W2[2 * n];
        const float w21 = W2[2 * n + 1];
        #pragma unroll
        for (int mt = 0; mt < 4; ++mt)
            #pragma unroll
            for (int rr = 0; rr < 4; ++rr) {
                float v = fmaxf(acc[mt][nt][rr] + bnv, 0.0f);
                p0[mt][rr] = fmaf(v, w20, p0[mt][rr]);
                p1[mt][rr] = fmaf(v, w21, p1[mt][rr]);
            }
    }
    #pragma unroll
    for (int mt = 0; mt < 4; ++mt)
        #pragma unroll
        for (int rr = 0; rr < 4; ++rr) {
            float a0 = p0[mt][rr], a1 = p1[mt][rr];
            #pragma unroll
            for (int mask = 1; mask < 16; mask <<= 1) {
                a0 += __shfl_xor(a0, mask);
                a1 += __shfl_xor(a1, mask);
            }
            p0[mt][rr] = a0; p1[mt][rr] = a1;
        }
    float* part = reinterpret_cast<float*>(lds + MTILE * 512);
    if (lc == 0) {
        #pragma unroll
        for (int mt = 0; mt < 4; ++mt)
            #pragma unroll
            for (int rr = 0; rr < 4; ++rr) {
                const int m = mt * 16 + lg * 4 + rr;
                part[(w * MTILE + m) * 2 + 0] = p0[mt][rr];
                part[(w * MTILE + m) * 2 + 1] = p1[mt][rr];
            }
    }
    __syncthreads();
    if (t < 2 * MTILE) {
        const int m = t >> 1, c = t & 1;
        if (e0 + m < npairs) {
            float s = b2[c];
            #pragma unroll
            for (int ww = 0; ww < 4; ++ww)
                s += part[(ww * MTILE + m) * 2 + c];
            out[(size_t)(e0 + m) * 2 + c] = s;
        }
    }
}

extern "C" void kernel_launch(void* const* d_in, const int* in_sizes, int n_in,
                              void* d_out, int out_size, void* d_ws, size_t ws_size,
                              hipStream_t stream) {
    const float* embs = (const float*)d_in[0];
    const int*   nidx = (const int*)d_in[1];
    const float* W1   = (const float*)d_in[2];
    const float* b1   = (const float*)d_in[3];
    const float* W2   = (const float*)d_in[4];
    const float* b2   = (const float*)d_in[5];
    float* out = (float*)d_out;

    const int nemb   = in_sizes[0];
    const int npairs = in_sizes[1] / 2;
    const int ntiles = (npairs + MTILE - 1) / MTILE;

    u16* w1p = (u16*)d_ws;                                   // 128 KiB @0
    prep_w1<<<(KDIM * HID) / 256, 256, 0, stream>>>(W1, w1p);

    const size_t w2_off   = 131072;
    const size_t hist_off = w2_off + 8192;                   // NBUCK ints
    const size_t cur_off  = hist_off + NBUCK * 4;
    const size_t embT_off = cur_off + NBUCK * 4;
    const size_t embT_end = embT_off + (size_t)nemb * 2;
    const size_t sp_off   = (embT_end + 255) & ~(size_t)255;
    const size_t se_off   = sp_off + (size_t)ntiles * 128 * 4;
    const size_t need_sort = se_off + (size_t)ntiles * 64 * 4;
    const size_t need_bf   = embT_end;

    if (ws_size >= need_bf) {
        u16* w2ap = (u16*)((char*)d_ws + w2_off);
        u16* embT = (u16*)((char*)d_ws + embT_off);
        prep_w2<<<16, 256, 0, stream>>>(W2, w2ap);
        prep_embs<<<(nemb + 2047) / 2048, 256, 0, stream>>>(embs, embT, nemb);

        if (ws_size >= need_sort) {
            int* hist    = (int*)((char*)d_ws + hist_off);
            int* cursor  = (int*)((char*)d_ws + cur_off);
            int* spairs  = (int*)((char*)d_ws + sp_off);
            int* seid    = (int*)((char*)d_ws + se_off);
            k_zero<<<1, 256, 0, stream>>>(hist, spairs, seid, npairs, ntiles);
            k_hist<<<256, 256, 0, stream>>>(nidx, npairs, hist);
            k_scan<<<1, 256, 0, stream>>>(hist, cursor);
            k_scatter2<<<256, 256, 0, stream>>>(nidx, npairs, cursor,
                                                (int2*)spairs, seid);
            const int nb = NBLK < ntiles ? NBLK : ntiles;
            const int q = ntiles / nb, rr = ntiles % nb;
            edge_mlp_bf6<<<nb, 256, 0, stream>>>(embT, spairs, seid, w1p, w2ap,
                                                 b1, b2, out, npairs, ntiles, q, rr);
        } else {
            const int nb = NBLK < ntiles ? NBLK : ntiles;
            edge_mlp_bf5<<<nb, 256, 0, stream>>>(embT, nidx, w1p, w2ap, b1, b2,
                                                 out, npairs, ntiles, nb);
        }
    } else {
        edge_mlp_f32g<<<ntiles, 256, 0, stream>>>(embs, nidx, w1p, b1, W2, b2,
                                                  out, npairs);
    }
}

// Round 10
// 158.549 us; speedup vs baseline: 2.5792x; 1.2762x over previous
//
#include <hip/hip_runtime.h>
#include <hip/hip_bf16.h>
#include <cstdint>
#include <cstddef>

typedef unsigned short u16;
typedef __bf16 bf16x8 __attribute__((ext_vector_type(8)));
typedef u16 ushort8 __attribute__((ext_vector_type(8)));
typedef float f32x4 __attribute__((ext_vector_type(4)));

#define EMB_DIM 128
#define KDIM 256
#define HID 256
#define MTILE 64
#define NBLK 512   // 2 blocks/CU * 256 CU

// LDS layout (bytes): X double-buffer + cross-wave partials
#define XB        (2 * MTILE * 512)    // 65536
#define PART_OFF  XB                   // 4096: 8 waves x 64 edges x float2
#define LDS_BYTES (XB + 4096)

static __device__ __forceinline__ u16 f2bf(float f) {
    uint32_t u = __builtin_bit_cast(uint32_t, f);
    u += 0x7fffu + ((u >> 16) & 1u);
    return (u16)(u >> 16);
}

// ---- prep kernels (validated R1-R8) ----
__global__ void prep_w1(const float* __restrict__ W1, u16* __restrict__ w1p) {
    int id = blockIdx.x * blockDim.x + threadIdx.x;   // 65536
    int j   = id & 7;
    int l   = (id >> 3) & 63;
    int kki = (id >> 9) & 7;
    int ntg = id >> 12;
    int k = kki * 32 + ((l >> 4) * 8) + j;
    int n = ntg * 16 + (l & 15);
    w1p[id] = f2bf(W1[k * HID + n]);
}

__global__ void prep_w2(const float* __restrict__ W2, u16* __restrict__ w2ap) {
    int id = blockIdx.x * blockDim.x + threadIdx.x;   // 4096
    if (id >= 4096) return;
    int j   = id & 7;
    int l   = (id >> 3) & 63;
    int kki = id >> 9;
    int m = l & 15;
    int g = (l >> 4) & 3;
    int k = kki * 32 + g * 4 + ((j >> 2) << 4) + (j & 3);
    w2ap[id] = (m < 2) ? f2bf(W2[k * 2 + m]) : (u16)0;
}

__global__ void prep_embs(const float* __restrict__ in, u16* __restrict__ out, int n) {
    int id = blockIdx.x * blockDim.x + threadIdx.x;
    size_t base = (size_t)id * 8;
    if (base + 8 <= (size_t)n) {
        float4 f0 = *reinterpret_cast<const float4*>(in + base);
        float4 f1 = *reinterpret_cast<const float4*>(in + base + 4);
        ushort8 h;
        h[0] = f2bf(f0.x); h[1] = f2bf(f0.y); h[2] = f2bf(f0.z); h[3] = f2bf(f0.w);
        h[4] = f2bf(f1.x); h[5] = f2bf(f1.y); h[6] = f2bf(f1.z); h[7] = f2bf(f1.w);
        *reinterpret_cast<ushort8*>(out + base) = h;
    }
}

static __device__ __forceinline__ void gload_lds16(const void* g, void* s) {
    __builtin_amdgcn_global_load_lds(
        (const __attribute__((address_space(1))) unsigned int*)g,
        (__attribute__((address_space(3))) unsigned int*)s, 16, 0, 0);
}

// 8-wave staging: wave w stages rows [w*8, w*8+8) (4 KB = 4 gload_lds16).
// vidx lanes 0..15 hold nidx[2*(tile*64 + w*8) + l]. Source-swizzled (R2-R8).
static __device__ __forceinline__ void stage_tile8(const u16* __restrict__ embT,
                                                   int vidx, unsigned char* xb,
                                                   int w, int l) {
    const int row_off = l >> 5;        // which of the 2 rows this lane fills
    const int csel    = (l >> 4) & 1;  // node0 vs node1 within a row
    const int c       = l & 31;        // 16B chunk within the 1KB (2-row) dest
    #pragma unroll
    for (int i = 0; i < 4; ++i) {
        int n00 = __builtin_amdgcn_readlane(vidx, 4 * i + 0);
        int n01 = __builtin_amdgcn_readlane(vidx, 4 * i + 1);
        int n10 = __builtin_amdgcn_readlane(vidx, 4 * i + 2);
        int n11 = __builtin_amdgcn_readlane(vidx, 4 * i + 3);
        int na   = csel ? n01 : n00;
        int nb   = csel ? n11 : n10;
        int node = row_off ? nb : na;
        int r2   = 2 * i + row_off;                 // (row&7): w*8 is 0 mod 8
        int glow = (c ^ (r2 & 7)) & 15;
        const u16* src = embT + (size_t)node * 128 + glow * 8;
        gload_lds16(src, xb + (size_t)(w * 8 + 2 * i) * 512);
    }
}

// ---- main kernel (R10 = R9 with compile fix): 8-wave re-partition ----
__launch_bounds__(512, 4)
__global__ void edge_mlp_bf7(const u16* __restrict__ embT,
                             const int* __restrict__ nidx,
                             const u16* __restrict__ w1p,
                             const u16* __restrict__ w2ap,
                             const float* __restrict__ b1,
                             const float* __restrict__ b2,
                             float* __restrict__ out,
                             int npairs, int ntiles, int nb) {
    __shared__ __align__(16) unsigned char lds[LDS_BYTES];
    const int t  = threadIdx.x;
    const int w  = t >> 6;     // wave 0..7 -> owns hidden [w*32, w*32+32)
    const int l  = t & 63;
    const int lg = l >> 4;
    const int lc = l & 15;
    const int gmax = 2 * npairs - 1;

    // ---- prologue: weights into registers, laundered (validated R6).
    // NOTE: "+v" tied constraints require ext_vector types (f32x4, bf16x8) —
    // HIP float4 struct fails with "tied indirect register inputs" (R9).
    bf16x8 wf1[2][8];
    #pragma unroll
    for (int ht = 0; ht < 2; ++ht)
        #pragma unroll
        for (int kki = 0; kki < 8; ++kki)
            wf1[ht][kki] = *reinterpret_cast<const bf16x8*>(
                w1p + (size_t)(((w * 2 + ht) * 8 + kki) * 64 + l) * 8);
    #pragma unroll
    for (int ht = 0; ht < 2; ++ht)
        #pragma unroll
        for (int kki = 0; kki < 8; ++kki)
            asm volatile("" : "+v"(wf1[ht][kki]));

    bf16x8 af2 = *reinterpret_cast<const bf16x8*>(w2ap + (size_t)(w * 64 + l) * 8);
    asm volatile("" : "+v"(af2));
    f32x4 b1v0 = *reinterpret_cast<const f32x4*>(b1 + w * 32 + lg * 4);
    f32x4 b1v1 = *reinterpret_cast<const f32x4*>(b1 + w * 32 + 16 + lg * 4);
    asm volatile("" : "+v"(b1v0));
    asm volatile("" : "+v"(b1v1));
    float b2c = b2[t & 1];
    asm volatile("" : "+v"(b2c));

    // per-lane LDS read base: addr(kki,et) = (base0 ^ (kki<<6)) + et*8192 (+buf)
    const int base0 = lc * 512 + ((lg ^ (lc & 3)) << 4) + (((lc >> 2) & 1) << 6);
    float2* part = reinterpret_cast<float2*>(lds + PART_OFF);

    int tile = blockIdx.x;

    // stage tile0 into buf0; prefetch indices for tile+nb
    {
        int gi = 2 * (tile * 64 + w * 8) + l;      // lanes 0..15 used
        int v0 = nidx[gi < gmax ? gi : gmax];
        stage_tile8(embT, v0, lds, w, l);
    }
    int vnext;
    {
        int gi = 2 * ((tile + nb) * 64 + w * 8) + l;
        vnext = nidx[gi < gmax ? gi : gmax];
    }

    int buf = 0;
    for (; tile < ntiles; tile += nb) {
        __syncthreads();   // sync1: stage(tile) complete (vmcnt0 drain)

        const int nxt = tile + nb;
        if (nxt < ntiles)
            stage_tile8(embT, vnext, lds + (buf ^ 1) * (MTILE * 512), w, l);
        int vfut;
        {
            int gi = 2 * ((nxt + nb) * 64 + w * 8) + l;
            vfut = nidx[gi < gmax ? gi : gmax];
        }

        // ---- GEMM1 (swapped): acc2[ht][et] = H^T[hidden][edge] ----
        const int vbuf = base0 + buf * (MTILE * 512);
        f32x4 acc2[2][4] = {};
        #pragma unroll
        for (int kki = 0; kki < 8; ++kki) {
            const int va = vbuf ^ (kki << 6);
            bf16x8 xf[4];
            #pragma unroll
            for (int et = 0; et < 4; ++et)
                xf[et] = *reinterpret_cast<const bf16x8*>(lds + va + et * 8192);
            #pragma unroll
            for (int ht = 0; ht < 2; ++ht)
                #pragma unroll
                for (int et = 0; et < 4; ++et)
                    acc2[ht][et] = __builtin_amdgcn_mfma_f32_16x16x32_bf16(
                        wf1[ht][kki], xf[et], acc2[ht][et], 0, 0, 0);
        }

        // ---- epilogue: relu(H+b1), pack, logits^T partial via 1 MFMA/et ----
        // wave w covers hidden chunk w (32 values) -> af2 chunk w
        #pragma unroll
        for (int et = 0; et < 4; ++et) {
            uint32_t wd[2][2];
            #pragma unroll
            for (int ht = 0; ht < 2; ++ht) {
                const f32x4 bv = ht ? b1v1 : b1v0;
                float v0 = fmaxf(acc2[ht][et][0] + bv[0], 0.0f);
                float v1 = fmaxf(acc2[ht][et][1] + bv[1], 0.0f);
                float v2 = fmaxf(acc2[ht][et][2] + bv[2], 0.0f);
                float v3 = fmaxf(acc2[ht][et][3] + bv[3], 0.0f);
                asm("v_cvt_pk_bf16_f32 %0, %1, %2" : "=v"(wd[ht][0]) : "v"(v0), "v"(v1));
                asm("v_cvt_pk_bf16_f32 %0, %1, %2" : "=v"(wd[ht][1]) : "v"(v2), "v"(v3));
            }
            int4 lo4 = make_int4(wd[0][0], wd[0][1], wd[1][0], wd[1][1]);
            f32x4 a3 = {0.0f, 0.0f, 0.0f, 0.0f};
            a3 = __builtin_amdgcn_mfma_f32_16x16x32_bf16(
                af2, __builtin_bit_cast(bf16x8, lo4), a3, 0, 0, 0);
            if (l < 16)
                part[w * 64 + et * 16 + l] = make_float2(a3[0], a3[1]);
        }

        // sync2: LDS-only barrier — keep stage DMAs in flight (validated R6)
        asm volatile("s_waitcnt lgkmcnt(0)\n\ts_barrier" ::: "memory");

        if (t < 128) {
            const float* pf = reinterpret_cast<const float*>(part);
            float s = b2c;
            #pragma unroll
            for (int ww = 0; ww < 8; ++ww)
                s += pf[ww * 128 + t];
            int m = t >> 1;
            if (tile * 64 + m < npairs)
                out[(size_t)tile * 128 + t] = s;
        }

        vnext = vfut;
        buf ^= 1;
    }
}

// ---- fallback (validated R1): f32 gather + VALU epilogue ----
__launch_bounds__(256, 2)
__global__ void edge_mlp_f32g(const float* __restrict__ embs,
                              const int* __restrict__ nidx,
                              const u16* __restrict__ w1p,
                              const float* __restrict__ b1,
                              const float* __restrict__ W2,
                              const float* __restrict__ b2,
                              float* __restrict__ out,
                              int npairs) {
    __shared__ __align__(16) unsigned char lds[MTILE * 512 + 4 * MTILE * 2 * 4];
    const int t  = threadIdx.x;
    const int e0 = blockIdx.x * MTILE;
    {
        const int row = t >> 2;
        const int seg = t & 3;
        const int e = e0 + row;
        if (e < npairs) {
            const int i0 = nidx[2 * e];
            const int i1 = nidx[2 * e + 1];
            const float* src = (seg < 2) ? (embs + (size_t)i0 * EMB_DIM)
                                         : (embs + (size_t)i1 * EMB_DIM);
            const int cbase = (seg & 1) * 64;
            #pragma unroll
            for (int j = 0; j < 8; ++j) {
                const int c = cbase + j * 8;
                float4 f0 = *reinterpret_cast<const float4*>(src + c);
                float4 f1 = *reinterpret_cast<const float4*>(src + c + 4);
                ushort8 h;
                h[0] = f2bf(f0.x); h[1] = f2bf(f0.y);
                h[2] = f2bf(f0.z); h[3] = f2bf(f0.w);
                h[4] = f2bf(f1.x); h[5] = f2bf(f1.y);
                h[6] = f2bf(f1.z); h[7] = f2bf(f1.w);
                int off = row * 512 + (seg * 64 + j * 8) * 2;
                off ^= (row & 7) << 4;
                *reinterpret_cast<ushort8*>(lds + off) = h;
            }
        }
    }
    __syncthreads();
    const int w  = t >> 6;
    const int l  = t & 63;
    const int lg = l >> 4;
    const int lc = l & 15;
    f32x4 acc[4][4] = {};
    #pragma unroll
    for (int kki = 0; kki < 8; ++kki) {
        const int krow = kki * 32 + lg * 8;
        bf16x8 a[4], bb[4];
        #pragma unroll
        for (int mt = 0; mt < 4; ++mt) {
            const int row = mt * 16 + lc;
            int off = row * 512 + krow * 2;
            off ^= (row & 7) << 4;
            a[mt] = *reinterpret_cast<const bf16x8*>(lds + off);
        }
        #pragma unroll
        for (int nt = 0; nt < 4; ++nt)
            bb[nt] = *reinterpret_cast<const bf16x8*>(
                w1p + (size_t)(((w * 4 + nt) * 8 + kki) * 64 + l) * 8);
        #pragma unroll
        for (int mt = 0; mt < 4; ++mt)
            #pragma unroll
            for (int nt = 0; nt < 4; ++nt)
                acc[mt][nt] = __builtin_amdgcn_mfma_f32_16x16x32_bf16(
                    a[mt], bb[nt], acc[mt][nt], 0, 0, 0);
    }
    float p0[4][4] = {}, p1[4][4] = {};
    #pragma unroll
    for (int nt = 0; nt < 4; ++nt) {
        const int n = w * 64 + nt * 16 + lc;
        const float bnv = b1[n];
        const float w20 = W2[2 * n];
        const float w21 = W2[2 * n + 1];
        #pragma unroll
        for (int mt = 0; mt < 4; ++mt)
            #pragma unroll
            for (int rr = 0; rr < 4; ++rr) {
                float v = fmaxf(acc[mt][nt][rr] + bnv, 0.0f);
                p0[mt][rr] = fmaf(v, w20, p0[mt][rr]);
                p1[mt][rr] = fmaf(v, w21, p1[mt][rr]);
            }
    }
    #pragma unroll
    for (int mt = 0; mt < 4; ++mt)
        #pragma unroll
        for (int rr = 0; rr < 4; ++rr) {
            float a0 = p0[mt][rr], a1 = p1[mt][rr];
            #pragma unroll
            for (int mask = 1; mask < 16; mask <<= 1) {
                a0 += __shfl_xor(a0, mask);
                a1 += __shfl_xor(a1, mask);
            }
            p0[mt][rr] = a0; p1[mt][rr] = a1;
        }
    float* part = reinterpret_cast<float*>(lds + MTILE * 512);
    if (lc == 0) {
        #pragma unroll
        for (int mt = 0; mt < 4; ++mt)
            #pragma unroll
            for (int rr = 0; rr < 4; ++rr) {
                const int m = mt * 16 + lg * 4 + rr;
                part[(w * MTILE + m) * 2 + 0] = p0[mt][rr];
                part[(w * MTILE + m) * 2 + 1] = p1[mt][rr];
            }
    }
    __syncthreads();
    if (t < 2 * MTILE) {
        const int m = t >> 1, c = t & 1;
        if (e0 + m < npairs) {
            float s = b2[c];
            #pragma unroll
            for (int ww = 0; ww < 4; ++ww)
                s += part[(ww * MTILE + m) * 2 + c];
            out[(size_t)(e0 + m) * 2 + c] = s;
        }
    }
}

extern "C" void kernel_launch(void* const* d_in, const int* in_sizes, int n_in,
                              void* d_out, int out_size, void* d_ws, size_t ws_size,
                              hipStream_t stream) {
    const float* embs = (const float*)d_in[0];
    const int*   nidx = (const int*)d_in[1];
    const float* W1   = (const float*)d_in[2];
    const float* b1   = (const float*)d_in[3];
    const float* W2   = (const float*)d_in[4];
    const float* b2   = (const float*)d_in[5];
    float* out = (float*)d_out;

    const int nemb   = in_sizes[0];
    const int npairs = in_sizes[1] / 2;
    const int ntiles = (npairs + MTILE - 1) / MTILE;

    u16* w1p = (u16*)d_ws;                                   // 128 KiB @0
    prep_w1<<<(KDIM * HID) / 256, 256, 0, stream>>>(W1, w1p);

    const size_t w2_off   = 131072;                          // 8 KiB
    const size_t embT_off = 131072 + 8192;
    const size_t need = embT_off + (size_t)nemb * 2;
    if (ws_size >= need) {
        u16* w2ap = (u16*)((char*)d_ws + w2_off);
        u16* embT = (u16*)((char*)d_ws + embT_off);
        prep_w2<<<16, 256, 0, stream>>>(W2, w2ap);
        prep_embs<<<(nemb + 2047) / 2048, 256, 0, stream>>>(embs, embT, nemb);
        const int nb = NBLK < ntiles ? NBLK : ntiles;
        edge_mlp_bf7<<<nb, 512, 0, stream>>>(embT, nidx, w1p, w2ap, b1, b2,
                                             out, npairs, ntiles, nb);
    } else {
        edge_mlp_f32g<<<ntiles, 256, 0, stream>>>(embs, nidx, w1p, b1, W2, b2,
                                                  out, npairs);
    }
}

// Round 11
// 150.815 us; speedup vs baseline: 2.7115x; 1.0513x over previous
//
#include <hip/hip_runtime.h>
#include <hip/hip_bf16.h>
#include <cstdint>
#include <cstddef>

typedef unsigned short u16;
typedef __bf16 bf16x8 __attribute__((ext_vector_type(8)));
typedef u16 ushort8 __attribute__((ext_vector_type(8)));
typedef float f32x4 __attribute__((ext_vector_type(4)));

#define EMB_DIM 128
#define KDIM 256
#define HID 256
#define MTILE 64
#define NBLK 512   // 2 blocks/CU * 256 CU (LDS-limited)

// LDS layout (bytes)
#define XB       (2 * MTILE * 512)   // 65536: X double-buffer
#define PART_OFF XB                  // 2048: cross-wave logit partials
#define B1_OFF   (XB + 2048)         // 1024: b1 (f32[256])
#define AF2_OFF  (XB + 3072)         // 8192: W2 A-fragments (copy of w2ap)
#define LDS_BYTES (XB + 2048 + 1024 + 8192)

static __device__ __forceinline__ u16 f2bf(float f) {
    uint32_t u = __builtin_bit_cast(uint32_t, f);
    u += 0x7fffu + ((u >> 16) & 1u);
    return (u16)(u >> 16);
}

// W1 [K=256][N=256] f32 -> MFMA fragment order, bf16 (validated R1-R10).
__global__ void prep_w1(const float* __restrict__ W1, u16* __restrict__ w1p) {
    int id = blockIdx.x * blockDim.x + threadIdx.x;   // 65536
    int j   = id & 7;
    int l   = (id >> 3) & 63;
    int kki = (id >> 9) & 7;
    int ntg = id >> 12;
    int k = kki * 32 + ((l >> 4) * 8) + j;
    int n = ntg * 16 + (l & 15);
    w1p[id] = f2bf(W1[k * HID + n]);
}

// W2 [256][2] -> A-fragment with permuted k-map matching raw cvt_pk'd acc words
// (validated R3-R10).
__global__ void prep_w2(const float* __restrict__ W2, u16* __restrict__ w2ap) {
    int id = blockIdx.x * blockDim.x + threadIdx.x;   // 4096
    if (id >= 4096) return;
    int j   = id & 7;
    int l   = (id >> 3) & 63;
    int kki = id >> 9;
    int m = l & 15;
    int g = (l >> 4) & 3;
    int k = kki * 32 + g * 4 + ((j >> 2) << 4) + (j & 3);
    w2ap[id] = (m < 2) ? f2bf(W2[k * 2 + m]) : (u16)0;
}

// Embedding table f32 -> bf16 (row-major).
__global__ void prep_embs(const float* __restrict__ in, u16* __restrict__ out, int n) {
    int id = blockIdx.x * blockDim.x + threadIdx.x;
    size_t base = (size_t)id * 8;
    if (base + 8 <= (size_t)n) {
        float4 f0 = *reinterpret_cast<const float4*>(in + base);
        float4 f1 = *reinterpret_cast<const float4*>(in + base + 4);
        ushort8 h;
        h[0] = f2bf(f0.x); h[1] = f2bf(f0.y); h[2] = f2bf(f0.z); h[3] = f2bf(f0.w);
        h[4] = f2bf(f1.x); h[5] = f2bf(f1.y); h[6] = f2bf(f1.z); h[7] = f2bf(f1.w);
        *reinterpret_cast<ushort8*>(out + base) = h;
    }
}

static __device__ __forceinline__ void gload_lds16(const void* g, void* s) {
    __builtin_amdgcn_global_load_lds(
        (const __attribute__((address_space(1))) unsigned int*)g,
        (__attribute__((address_space(3))) unsigned int*)s, 16, 0, 0);
}

// Stage 16 edge rows (wave w) of gathered bf16 X into LDS, source-swizzled
// (validated R2-R10).
static __device__ __forceinline__ void stage_tile(const u16* __restrict__ embT,
                                                  int vidx, unsigned char* xb,
                                                  int w, int l) {
    const int row_off = l >> 5;
    const int csel    = (l >> 4) & 1;
    const int c       = l & 31;
    #pragma unroll
    for (int i = 0; i < 8; ++i) {
        int n00 = __builtin_amdgcn_readlane(vidx, 4 * i + 0);
        int n01 = __builtin_amdgcn_readlane(vidx, 4 * i + 1);
        int n10 = __builtin_amdgcn_readlane(vidx, 4 * i + 2);
        int n11 = __builtin_amdgcn_readlane(vidx, 4 * i + 3);
        int na   = csel ? n01 : n00;
        int nb   = csel ? n11 : n10;
        int node = row_off ? nb : na;
        int r2   = 2 * i + row_off;
        int glow = (c ^ (r2 & 7)) & 15;
        const u16* src = embT + (size_t)node * 128 + glow * 8;
        gload_lds16(src, xb + (size_t)(w * 16 + 2 * i) * 512);
    }
}

// ---- main kernel: best validated config (R6, 141-142us) ----
__launch_bounds__(256, 2)
__global__ void edge_mlp_bf5(const u16* __restrict__ embT,
                             const int* __restrict__ nidx,
                             const u16* __restrict__ w1p,
                             const u16* __restrict__ w2ap,
                             const float* __restrict__ b1,
                             const float* __restrict__ b2,
                             float* __restrict__ out,
                             int npairs, int ntiles, int nb) {
    __shared__ __align__(16) unsigned char lds[LDS_BYTES];
    const int t  = threadIdx.x;
    const int w  = t >> 6;
    const int l  = t & 63;
    const int lg = l >> 4;
    const int lc = l & 15;
    const int gmax = 2 * npairs - 1;

    // W1 -> registers via normal loads, laundered against remat (validated R6).
    bf16x8 wf1[4][8];
    #pragma unroll
    for (int ht = 0; ht < 4; ++ht)
        #pragma unroll
        for (int kki = 0; kki < 8; ++kki)
            wf1[ht][kki] = *reinterpret_cast<const bf16x8*>(
                w1p + (size_t)(((w * 4 + ht) * 8 + kki) * 64 + l) * 8);
    #pragma unroll
    for (int ht = 0; ht < 4; ++ht)
        #pragma unroll
        for (int kki = 0; kki < 8; ++kki)
            asm volatile("" : "+v"(wf1[ht][kki]));

    float b2c = b2[t & 1];
    asm volatile("" : "+v"(b2c));

    // b1 / W2-fragments -> LDS (in-loop reads are lgkmcnt-only).
    if (w == 0) {
        gload_lds16(b1 + l * 4, lds + B1_OFF);
    } else if (w == 1) {
        #pragma unroll
        for (int i = 0; i < 8; ++i)
            gload_lds16(w2ap + (size_t)i * 512 + l * 8, lds + AF2_OFF + i * 1024);
    }

    const int base0 = lc * 512 + ((lg ^ (lc & 3)) << 4) + (((lc >> 2) & 1) << 6);
    float2* part = reinterpret_cast<float2*>(lds + PART_OFF);

    int tile = blockIdx.x;
    {
        int gi = 2 * (tile * 64 + w * 16) + l;
        int v0 = nidx[gi < gmax ? gi : gmax];
        stage_tile(embT, v0, lds, w, l);
    }
    int vnext;
    {
        int gi = 2 * ((tile + nb) * 64 + w * 16) + l;
        vnext = nidx[gi < gmax ? gi : gmax];
    }

    int buf = 0;
    for (; tile < ntiles; tile += nb) {
        __syncthreads();   // sync1: stage(tile) + prologue DMAs complete

        const int nxt = tile + nb;
        if (nxt < ntiles)
            stage_tile(embT, vnext, lds + (buf ^ 1) * (MTILE * 512), w, l);
        int vfut;
        {
            int gi = 2 * ((nxt + nb) * 64 + w * 16) + l;
            vfut = nidx[gi < gmax ? gi : gmax];
        }

        // GEMM1 (swapped): acc2[ht][et] = H^T[hidden][edge]; VMEM-free loop.
        const int vbuf = base0 + buf * (MTILE * 512);
        f32x4 acc2[4][4] = {};
        #pragma unroll
        for (int kki = 0; kki < 8; ++kki) {
            const int va = vbuf ^ (kki << 6);
            bf16x8 xf[4];
            #pragma unroll
            for (int et = 0; et < 4; ++et)
                xf[et] = *reinterpret_cast<const bf16x8*>(lds + va + et * 8192);
            #pragma unroll
            for (int ht = 0; ht < 4; ++ht)
                #pragma unroll
                for (int et = 0; et < 4; ++et)
                    acc2[ht][et] = __builtin_amdgcn_mfma_f32_16x16x32_bf16(
                        wf1[ht][kki], xf[et], acc2[ht][et], 0, 0, 0);
        }

        // epilogue: relu(H+b1) then logits^T = W2^T @ . via MFMA
        float4 b1v[4];
        #pragma unroll
        for (int ht = 0; ht < 4; ++ht)
            b1v[ht] = *reinterpret_cast<const float4*>(
                lds + B1_OFF + (w * 64 + ht * 16 + lg * 4) * 4);
        bf16x8 af2[2];
        #pragma unroll
        for (int kk = 0; kk < 2; ++kk)
            af2[kk] = *reinterpret_cast<const bf16x8*>(
                lds + AF2_OFF + ((w * 2 + kk) * 64 + l) * 16);

        #pragma unroll
        for (int et = 0; et < 4; ++et) {
            uint32_t wd[4][2];
            #pragma unroll
            for (int ht = 0; ht < 4; ++ht) {
                float v0 = fmaxf(acc2[ht][et][0] + b1v[ht].x, 0.0f);
                float v1 = fmaxf(acc2[ht][et][1] + b1v[ht].y, 0.0f);
                float v2 = fmaxf(acc2[ht][et][2] + b1v[ht].z, 0.0f);
                float v3 = fmaxf(acc2[ht][et][3] + b1v[ht].w, 0.0f);
                asm("v_cvt_pk_bf16_f32 %0, %1, %2" : "=v"(wd[ht][0]) : "v"(v0), "v"(v1));
                asm("v_cvt_pk_bf16_f32 %0, %1, %2" : "=v"(wd[ht][1]) : "v"(v2), "v"(v3));
            }
            int4 lo4 = make_int4(wd[0][0], wd[0][1], wd[1][0], wd[1][1]);
            int4 hi4 = make_int4(wd[2][0], wd[2][1], wd[3][0], wd[3][1]);
            f32x4 a3 = {0.0f, 0.0f, 0.0f, 0.0f};
            a3 = __builtin_amdgcn_mfma_f32_16x16x32_bf16(
                af2[0], __builtin_bit_cast(bf16x8, lo4), a3, 0, 0, 0);
            a3 = __builtin_amdgcn_mfma_f32_16x16x32_bf16(
                af2[1], __builtin_bit_cast(bf16x8, hi4), a3, 0, 0, 0);
            if (l < 16)
                part[w * 64 + et * 16 + l] = make_float2(a3[0], a3[1]);
        }

        // sync2: LDS-only barrier — keep stage DMAs in flight
        asm volatile("s_waitcnt lgkmcnt(0)\n\ts_barrier" ::: "memory");

        if (t < 128) {
            const float* pf = reinterpret_cast<const float*>(part);
            float s = b2c + pf[t] + pf[128 + t] + pf[256 + t] + pf[384 + t];
            int m = t >> 1;
            if (tile * 64 + m < npairs)
                out[(size_t)tile * 128 + t] = s;
        }

        vnext = vfut;
        buf ^= 1;
    }
}

// ---- fallback (validated R1): f32 gather + in-kernel convert, VALU epilogue ----
__launch_bounds__(256, 2)
__global__ void edge_mlp_f32g(const float* __restrict__ embs,
                              const int* __restrict__ nidx,
                              const u16* __restrict__ w1p,
                              const float* __restrict__ b1,
                              const float* __restrict__ W2,
                              const float* __restrict__ b2,
                              float* __restrict__ out,
                              int npairs) {
    __shared__ __align__(16) unsigned char lds[MTILE * 512 + 4 * MTILE * 2 * 4];
    const int t  = threadIdx.x;
    const int e0 = blockIdx.x * MTILE;
    {
        const int row = t >> 2;
        const int seg = t & 3;
        const int e = e0 + row;
        if (e < npairs) {
            const int i0 = nidx[2 * e];
            const int i1 = nidx[2 * e + 1];
            const float* src = (seg < 2) ? (embs + (size_t)i0 * EMB_DIM)
                                         : (embs + (size_t)i1 * EMB_DIM);
            const int cbase = (seg & 1) * 64;
            #pragma unroll
            for (int j = 0; j < 8; ++j) {
                const int c = cbase + j * 8;
                float4 f0 = *reinterpret_cast<const float4*>(src + c);
                float4 f1 = *reinterpret_cast<const float4*>(src + c + 4);
                ushort8 h;
                h[0] = f2bf(f0.x); h[1] = f2bf(f0.y);
                h[2] = f2bf(f0.z); h[3] = f2bf(f0.w);
                h[4] = f2bf(f1.x); h[5] = f2bf(f1.y);
                h[6] = f2bf(f1.z); h[7] = f2bf(f1.w);
                int off = row * 512 + (seg * 64 + j * 8) * 2;
                off ^= (row & 7) << 4;
                *reinterpret_cast<ushort8*>(lds + off) = h;
            }
        }
    }
    __syncthreads();
    const int w  = t >> 6;
    const int l  = t & 63;
    const int lg = l >> 4;
    const int lc = l & 15;
    f32x4 acc[4][4] = {};
    #pragma unroll
    for (int kki = 0; kki < 8; ++kki) {
        const int krow = kki * 32 + lg * 8;
        bf16x8 a[4], bb[4];
        #pragma unroll
        for (int mt = 0; mt < 4; ++mt) {
            const int row = mt * 16 + lc;
            int off = row * 512 + krow * 2;
            off ^= (row & 7) << 4;
            a[mt] = *reinterpret_cast<const bf16x8*>(lds + off);
        }
        #pragma unroll
        for (int nt = 0; nt < 4; ++nt)
            bb[nt] = *reinterpret_cast<const bf16x8*>(
                w1p + (size_t)(((w * 4 + nt) * 8 + kki) * 64 + l) * 8);
        #pragma unroll
        for (int mt = 0; mt < 4; ++mt)
            #pragma unroll
            for (int nt = 0; nt < 4; ++nt)
                acc[mt][nt] = __builtin_amdgcn_mfma_f32_16x16x32_bf16(
                    a[mt], bb[nt], acc[mt][nt], 0, 0, 0);
    }
    float p0[4][4] = {}, p1[4][4] = {};
    #pragma unroll
    for (int nt = 0; nt < 4; ++nt) {
        const int n = w * 64 + nt * 16 + lc;
        const float bnv = b1[n];
        const float w20 = W2[2 * n];
        const float w21 = W2[2 * n + 1];
        #pragma unroll
        for (int mt = 0; mt < 4; ++mt)
            #pragma unroll
            for (int rr = 0; rr < 4; ++rr) {
                float v = fmaxf(acc[mt][nt][rr] + bnv, 0.0f);
                p0[mt][rr] = fmaf(v, w20, p0[mt][rr]);
                p1[mt][rr] = fmaf(v, w21, p1[mt][rr]);
            }
    }
    #pragma unroll
    for (int mt = 0; mt < 4; ++mt)
        #pragma unroll
        for (int rr = 0; rr < 4; ++rr) {
            float a0 = p0[mt][rr], a1 = p1[mt][rr];
            #pragma unroll
            for (int mask = 1; mask < 16; mask <<= 1) {
                a0 += __shfl_xor(a0, mask);
                a1 += __shfl_xor(a1, mask);
            }
            p0[mt][rr] = a0; p1[mt][rr] = a1;
        }
    float* part = reinterpret_cast<float*>(lds + MTILE * 512);
    if (lc == 0) {
        #pragma unroll
        for (int mt = 0; mt < 4; ++mt)
            #pragma unroll
            for (int rr = 0; rr < 4; ++rr) {
                const int m = mt * 16 + lg * 4 + rr;
                part[(w * MTILE + m) * 2 + 0] = p0[mt][rr];
                part[(w * MTILE + m) * 2 + 1] = p1[mt][rr];
            }
    }
    __syncthreads();
    if (t < 2 * MTILE) {
        const int m = t >> 1, c = t & 1;
        if (e0 + m < npairs) {
            float s = b2[c];
            #pragma unroll
            for (int ww = 0; ww < 4; ++ww)
                s += part[(ww * MTILE + m) * 2 + c];
            out[(size_t)(e0 + m) * 2 + c] = s;
        }
    }
}

extern "C" void kernel_launch(void* const* d_in, const int* in_sizes, int n_in,
                              void* d_out, int out_size, void* d_ws, size_t ws_size,
                              hipStream_t stream) {
    const float* embs = (const float*)d_in[0];
    const int*   nidx = (const int*)d_in[1];
    const float* W1   = (const float*)d_in[2];
    const float* b1   = (const float*)d_in[3];
    const float* W2   = (const float*)d_in[4];
    const float* b2   = (const float*)d_in[5];
    float* out = (float*)d_out;

    const int nemb   = in_sizes[0];
    const int npairs = in_sizes[1] / 2;
    const int ntiles = (npairs + MTILE - 1) / MTILE;

    u16* w1p = (u16*)d_ws;                                   // 128 KiB @0
    prep_w1<<<(KDIM * HID) / 256, 256, 0, stream>>>(W1, w1p);

    const size_t w2_off   = 131072;                          // 8 KiB
    const size_t embT_off = 131072 + 8192;
    const size_t need = embT_off + (size_t)nemb * 2;
    if (ws_size >= need) {
        u16* w2ap = (u16*)((char*)d_ws + w2_off);
        u16* embT = (u16*)((char*)d_ws + embT_off);
        prep_w2<<<16, 256, 0, stream>>>(W2, w2ap);
        prep_embs<<<(nemb + 2047) / 2048, 256, 0, stream>>>(embs, embT, nemb);
        const int nb = NBLK < ntiles ? NBLK : ntiles;
        edge_mlp_bf5<<<nb, 256, 0, stream>>>(embT, nidx, w1p, w2ap, b1, b2,
                                             out, npairs, ntiles, nb);
    } else {
        edge_mlp_f32g<<<ntiles, 256, 0, stream>>>(embs, nidx, w1p, b1, W2, b2,
                                                  out, npairs);
    }
}